// Round 3
// baseline (3996.014 us; speedup 1.0000x reference)
//
#include <hip/hip_runtime.h>
#include <hip/hip_bf16.h>
#include <math.h>

typedef __hip_bfloat16 bf16;

// Problem constants (fixed by reference)
#define B_      8
#define S_      2048
#define DIN     1024
#define DSTATE  1024
#define H_      16
#define DH_     64
#define PROJ4   4096   // 4*DSTATE

// ---------------------------------------------------------------------------
// bf16 <-> f32 helpers (bit-level, RNE for store)
// ---------------------------------------------------------------------------
__device__ __forceinline__ unsigned short f2bf(float f) {
    unsigned int x = __float_as_uint(f);
    x += 0x7FFFu + ((x >> 16) & 1u);   // round-to-nearest-even
    return (unsigned short)(x >> 16);
}

// 4-element vector load/store, overloaded on element type
__device__ __forceinline__ float4 load4(const float* p) { return *(const float4*)p; }
__device__ __forceinline__ float4 load4(const bf16* p) {
    uint2 u = *(const uint2*)p;    // 4 bf16 = 8 bytes
    float4 r;
    r.x = __uint_as_float((u.x & 0xFFFFu) << 16);
    r.y = __uint_as_float(u.x & 0xFFFF0000u);
    r.z = __uint_as_float((u.y & 0xFFFFu) << 16);
    r.w = __uint_as_float(u.y & 0xFFFF0000u);
    return r;
}
__device__ __forceinline__ void store4(float* p, float4 v) { *(float4*)p = v; }
__device__ __forceinline__ void store4(bf16* p, float4 v) {
    uint2 u;
    u.x = (unsigned int)f2bf(v.x) | ((unsigned int)f2bf(v.y) << 16);
    u.y = (unsigned int)f2bf(v.z) | ((unsigned int)f2bf(v.w) << 16);
    *(uint2*)p = u;
}

// ---------------------------------------------------------------------------
// GEMM: C[M,N] = A[M,K] @ B[K,N]; A has row stride lda (elements), B,C dense.
// fp32 accumulate; A may be fp32 or bf16, C may be fp32 or bf16.
// 128x128 tile, BK=8, 256 threads, 8x8 micro-tile split 4+4 (2-way LDS
// aliasing only, which is free on gfx950).
// ---------------------------------------------------------------------------
template <typename TA, typename TC>
__global__ __launch_bounds__(256) void gemm128(const TA* __restrict__ A,
                                               const float* __restrict__ Bm,
                                               TC* __restrict__ C,
                                               int M, int N, int K, int lda) {
    __shared__ float As[8][128];   // As[k][m]
    __shared__ float Bs[8][128];   // Bs[k][n]

    const int tid = threadIdx.x;
    const int tx = tid & 15;
    const int ty = tid >> 4;
    const int m0 = blockIdx.y * 128;
    const int n0 = blockIdx.x * 128;

    const int aRow = tid >> 1;        // 0..127
    const int aCol = (tid & 1) * 4;   // 0 or 4
    const int bRow = tid >> 5;        // 0..7
    const int bCol = (tid & 31) * 4;  // 0..124

    const TA* Aptr = A + (size_t)(m0 + aRow) * lda + aCol;
    const float* Bptr = Bm + (size_t)bRow * N + n0 + bCol;

    float acc[8][8];
    #pragma unroll
    for (int i = 0; i < 8; ++i)
        #pragma unroll
        for (int j = 0; j < 8; ++j) acc[i][j] = 0.0f;

    for (int k0 = 0; k0 < K; k0 += 8) {
        float4 av = load4(Aptr + k0);
        float4 bv = load4(Bptr + (size_t)k0 * N);
        __syncthreads();
        As[aCol + 0][aRow] = av.x;
        As[aCol + 1][aRow] = av.y;
        As[aCol + 2][aRow] = av.z;
        As[aCol + 3][aRow] = av.w;
        *(float4*)&Bs[bRow][bCol] = bv;
        __syncthreads();

        #pragma unroll
        for (int kk = 0; kk < 8; ++kk) {
            float4 a0 = *(const float4*)&As[kk][ty * 4];
            float4 a1 = *(const float4*)&As[kk][64 + ty * 4];
            float4 b0 = *(const float4*)&Bs[kk][tx * 4];
            float4 b1 = *(const float4*)&Bs[kk][64 + tx * 4];
            float a[8] = {a0.x, a0.y, a0.z, a0.w, a1.x, a1.y, a1.z, a1.w};
            float b[8] = {b0.x, b0.y, b0.z, b0.w, b1.x, b1.y, b1.z, b1.w};
            #pragma unroll
            for (int i = 0; i < 8; ++i)
                #pragma unroll
                for (int j = 0; j < 8; ++j)
                    acc[i][j] = fmaf(a[i], b[j], acc[i][j]);
        }
    }

    #pragma unroll
    for (int i = 0; i < 8; ++i) {
        int m = (i < 4) ? (ty * 4 + i) : (64 + ty * 4 + (i - 4));
        TC* cp = C + (size_t)(m0 + m) * N + n0;
        float4 v0 = {acc[i][0], acc[i][1], acc[i][2], acc[i][3]};
        float4 v1 = {acc[i][4], acc[i][5], acc[i][6], acc[i][7]};
        store4(cp + tx * 4, v0);
        store4(cp + 64 + tx * 4, v1);
    }
}

// ---------------------------------------------------------------------------
// Recurrence, 4 waves per (b,h) chain.
// Wave w owns d-slice [16w, 16w+16) of Wc/Wf/Wr (lane e holds column e).
// Each wave keeps a full replica of h (lane e holds h[e]); partial matvec
// sums are reduced through LDS (2 barriers/step). All waves recompute the
// identical r/f/c/h update bitwise, so no cross-wave h broadcast is needed.
// h_t is written IN PLACE over the consumed xi slot by wave 0 only.
// ---------------------------------------------------------------------------
__device__ __forceinline__ float lane_bcast(float v, int lane) {
    return __int_as_float(__builtin_amdgcn_readlane(__float_as_int(v), lane));
}

__global__ __launch_bounds__(256, 1) void recur_kernel(bf16* __restrict__ proj,
                                                       const float* __restrict__ sw) {
    const int tid = threadIdx.x;
    const int e = tid & 63;                 // output element this lane owns
    const int bh = blockIdx.x;              // 0..127
    const int b = bh >> 4;
    const int h = bh & 15;
    // wave-uniform d-slice base, forced to SGPR so readlane gets a uniform idx
    const int d0 = __builtin_amdgcn_readfirstlane((tid >> 6) << 4);
    const int w = d0 >> 4;

    __shared__ float2 part_rf[4][64];
    __shared__ float  part_c[4][64];

    // state_weight [3*H, 64, 64]: Wc = sw[h], Wf = sw[16+h], Wr = sw[32+h]
    const float* Wc_p = sw + (size_t)h * 4096 + (size_t)d0 * 64 + e;
    const float* Wf_p = Wc_p + (size_t)16 * 4096;
    const float* Wr_p = Wc_p + (size_t)32 * 4096;

    float Wc[16], Wf[16], Wr[16];
    #pragma unroll
    for (int d = 0; d < 16; ++d) {
        Wc[d] = Wc_p[d * 64];
        Wf[d] = Wf_p[d * 64];
        Wr[d] = Wr_p[d * 64];
    }

    bf16* xi_p = proj + (size_t)b * S_ * PROJ4 + h * 64 + e;   // cols [0:1024)
    const bf16* xf_p = xi_p + 1024;
    const bf16* xr_p = xi_p + 2048;

    float hreg = 0.0f;

    // depth-2 prefetch: step time (~500 cyc) < L3/HBM latency, so 1-deep
    // prefetch would stall; 2-deep gives ~1000+ cyc of cover.
    float xi0 = __bfloat162float(xi_p[0]);
    float xf0 = __bfloat162float(xf_p[0]);
    float xr0 = __bfloat162float(xr_p[0]);
    float xi1 = __bfloat162float(xi_p[PROJ4]);
    float xf1 = __bfloat162float(xf_p[PROJ4]);
    float xr1 = __bfloat162float(xr_p[PROJ4]);

    for (int t = 0; t < S_; ++t) {
        float xi2 = 0.f, xf2 = 0.f, xr2 = 0.f;
        if (t + 2 < S_) {
            size_t o = (size_t)(t + 2) * PROJ4;
            xi2 = __bfloat162float(xi_p[o]);
            xf2 = __bfloat162float(xf_p[o]);
            xr2 = __bfloat162float(xr_p[o]);
        }

        // r/f partial matvecs over this wave's d-slice (shared h broadcast)
        float ar0 = 0.f, ar1 = 0.f, af0 = 0.f, af1 = 0.f;
        #pragma unroll
        for (int d = 0; d < 16; d += 2) {
            float hv0 = lane_bcast(hreg, d0 + d);
            float hv1 = lane_bcast(hreg, d0 + d + 1);
            ar0 = fmaf(hv0, Wr[d],     ar0);
            ar1 = fmaf(hv1, Wr[d + 1], ar1);
            af0 = fmaf(hv0, Wf[d],     af0);
            af1 = fmaf(hv1, Wf[d + 1], af1);
        }
        part_rf[w][e] = make_float2(ar0 + ar1, af0 + af1);
        __syncthreads();                                   // barrier 1

        float sr = xr0, sf = xf0;
        #pragma unroll
        for (int ww = 0; ww < 4; ++ww) {
            float2 p = part_rf[ww][e];
            sr += p.x;
            sf += p.y;
        }
        float r = 1.f / (1.f + __expf(-sr));
        float f = 1.f / (1.f + __expf(-sf));

        // candidate partial matvec on (r*h)
        float rh = r * hreg;
        float ac0 = 0.f, ac1 = 0.f;
        #pragma unroll
        for (int d = 0; d < 16; d += 2) {
            ac0 = fmaf(lane_bcast(rh, d0 + d),     Wc[d],     ac0);
            ac1 = fmaf(lane_bcast(rh, d0 + d + 1), Wc[d + 1], ac1);
        }
        part_c[w][e] = ac0 + ac1;
        __syncthreads();                                   // barrier 2

        float sc = xi0 + part_c[0][e] + part_c[1][e] + part_c[2][e] + part_c[3][e];
        sc = fminf(fmaxf(sc, -15.f), 15.f);
        float ex = __expf(-2.f * sc);
        float c = (1.f - ex) / (1.f + ex);                 // tanh

        hreg = f * hreg + (1.f - f) * c;                   // identical in all waves
        if (w == 0)
            xi_p[(size_t)t * PROJ4] = __float2bfloat16(hreg);

        xi0 = xi1; xf0 = xf1; xr0 = xr1;
        xi1 = xi2; xf1 = xf2; xr1 = xr2;
    }
}

// ---------------------------------------------------------------------------
// Gated RMSNorm in place: y = rmsnorm(h * silu(g)) * nw over proj cols [0:1024).
// One 256-thread block per row, 4 elements/thread.
// ---------------------------------------------------------------------------
__global__ __launch_bounds__(256) void gate_norm_kernel(bf16* __restrict__ proj,
                                                        const float* __restrict__ nw) {
    const int row = blockIdx.x;        // 0 .. B*S-1
    const int tid = threadIdx.x;
    __shared__ float red[4];

    bf16* hp = proj + (size_t)row * PROJ4;        // h in cols [0:1024)
    const bf16* gp = hp + 3 * DSTATE;             // g in cols [3072:4096)

    float4 hv = load4(hp + tid * 4);
    float4 gv = load4(gp + tid * 4);

    float v0 = hv.x * (gv.x / (1.f + __expf(-gv.x)));
    float v1 = hv.y * (gv.y / (1.f + __expf(-gv.y)));
    float v2 = hv.z * (gv.z / (1.f + __expf(-gv.z)));
    float v3 = hv.w * (gv.w / (1.f + __expf(-gv.w)));

    float ss = v0 * v0 + v1 * v1 + v2 * v2 + v3 * v3;
    #pragma unroll
    for (int mask = 32; mask >= 1; mask >>= 1)
        ss += __shfl_xor(ss, mask, 64);

    const int wid = tid >> 6;
    if ((tid & 63) == 0) red[wid] = ss;
    __syncthreads();
    float tot = red[0] + red[1] + red[2] + red[3];
    float scale = rsqrtf(tot * (1.0f / (float)DSTATE) + 1e-6f);

    float4 nv = *(const float4*)(nw + tid * 4);
    float4 y;
    y.x = v0 * scale * nv.x;
    y.y = v1 * scale * nv.y;
    y.z = v2 * scale * nv.z;
    y.w = v3 * scale * nv.w;
    store4(hp + tid * 4, y);
}

// ---------------------------------------------------------------------------
extern "C" void kernel_launch(void* const* d_in, const int* in_sizes, int n_in,
                              void* d_out, int out_size, void* d_ws, size_t ws_size,
                              hipStream_t stream) {
    const float* x     = (const float*)d_in[0];   // [B,S,DIN]
    const float* w_in  = (const float*)d_in[1];   // [DIN, 4*DSTATE]
    const float* sw    = (const float*)d_in[2];   // [3H, DH, DH]
    const float* nw    = (const float*)d_in[3];   // [DSTATE]
    const float* w_out = (const float*)d_in[4];   // [DSTATE, DOUT]
    float* out = (float*)d_out;

    bf16* proj = (bf16*)d_ws;    // [B*S, 4096] bf16 = 134 MB (only ws use)

    // 1) input projection GEMM: [16384,1024]f32 @ [1024,4096]f32 -> bf16
    dim3 g1(PROJ4 / 128, (B_ * S_) / 128);
    gemm128<float, bf16><<<g1, 256, 0, stream>>>(x, w_in, proj,
                                                 B_ * S_, PROJ4, DIN, DIN);

    // 2) sequential gated recurrence: 4 waves/chain, h_t overwrites xi slot
    recur_kernel<<<128, 256, 0, stream>>>(proj, sw);

    // 3) gate + rmsnorm in place over cols 0:1024
    gate_norm_kernel<<<B_ * S_, 256, 0, stream>>>(proj, nw);

    // 4) output projection GEMM: y(bf16, lda=4096) @ [1024,1024]f32 -> f32 out
    dim3 g2(DSTATE / 128, (B_ * S_) / 128);
    gemm128<bf16, float><<<g2, 256, 0, stream>>>(proj, w_out, out,
                                                 B_ * S_, DSTATE, DSTATE, PROJ4);
}

// Round 4
// 2354.208 us; speedup vs baseline: 1.6974x; 1.6974x over previous
//
#include <hip/hip_runtime.h>
#include <hip/hip_bf16.h>
#include <math.h>

typedef __hip_bfloat16 bf16;

// Problem constants (fixed by reference)
#define B_      8
#define S_      2048
#define DIN     1024
#define DSTATE  1024
#define H_      16
#define DH_     64
#define PROJ4   4096   // 4*DSTATE

// Barrier that does NOT drain vmcnt: LDS ordering only. Keeps global
// prefetch loads / stores in flight across the barrier (R3 post-mortem:
// __syncthreads' vmcnt(0) drain was costing ~1 memory latency per step).
#define BARRIER_LGKM() asm volatile("s_waitcnt lgkmcnt(0)\n\ts_barrier" ::: "memory")

// ---------------------------------------------------------------------------
// bf16 <-> f32 helpers (bit-level, RNE for store)
// ---------------------------------------------------------------------------
__device__ __forceinline__ unsigned short f2bf(float f) {
    unsigned int x = __float_as_uint(f);
    x += 0x7FFFu + ((x >> 16) & 1u);   // round-to-nearest-even
    return (unsigned short)(x >> 16);
}

__device__ __forceinline__ float4 load4(const float* p) { return *(const float4*)p; }
__device__ __forceinline__ float4 load4(const bf16* p) {
    uint2 u = *(const uint2*)p;    // 4 bf16 = 8 bytes
    float4 r;
    r.x = __uint_as_float((u.x & 0xFFFFu) << 16);
    r.y = __uint_as_float(u.x & 0xFFFF0000u);
    r.z = __uint_as_float((u.y & 0xFFFFu) << 16);
    r.w = __uint_as_float(u.y & 0xFFFF0000u);
    return r;
}
__device__ __forceinline__ void store4(float* p, float4 v) { *(float4*)p = v; }
__device__ __forceinline__ void store4(bf16* p, float4 v) {
    uint2 u;
    u.x = (unsigned int)f2bf(v.x) | ((unsigned int)f2bf(v.y) << 16);
    u.y = (unsigned int)f2bf(v.z) | ((unsigned int)f2bf(v.w) << 16);
    *(uint2*)p = u;
}

// ---------------------------------------------------------------------------
// MFMA bf16 GEMM: C[M,N] = A[M,K] @ B[K,N]; A row stride lda; B,C dense.
// 128x128 tile, BK=32, 256 threads = 4 waves (2x2), each wave 64x64 via a
// 4x4 grid of mfma_f32_16x16x32_bf16. fp32 operands are converted to bf16
// during LDS staging. LDS rows padded to 40 shorts (80 B: 16B-aligned,
// bank-spread). A frags and B frags are both ds_read_b128 (k-contiguous;
// B stored transposed as Bs[n][k]).
// Frag layouts (m89/m120-verified): A[m=lane&15][k=quad*8+j],
// B[k=quad*8+j][n=lane&15], D: col=lane&15, row=quad*4+reg.
// ---------------------------------------------------------------------------
typedef __attribute__((ext_vector_type(8))) short bf16x8;
typedef __attribute__((ext_vector_type(4))) float f32x4;
typedef __attribute__((ext_vector_type(4))) short short4v;

template <typename TA>
__device__ __forceinline__ void load_a4(const TA* p, float out[4]);
template <>
__device__ __forceinline__ void load_a4<float>(const float* p, float out[4]) {
    float4 v = *(const float4*)p;
    out[0] = v.x; out[1] = v.y; out[2] = v.z; out[3] = v.w;
}
template <>
__device__ __forceinline__ void load_a4<bf16>(const bf16* p, float out[4]) {
    float4 v = load4(p);
    out[0] = v.x; out[1] = v.y; out[2] = v.z; out[3] = v.w;
}

template <typename TA, typename TC>
__global__ __launch_bounds__(256) void gemm_mfma(const TA* __restrict__ A,
                                                 const float* __restrict__ Bm,
                                                 TC* __restrict__ C,
                                                 int M, int N, int K, int lda) {
    __shared__ short As[128][40];   // As[m][k], k contiguous
    __shared__ short Bs[128][40];   // Bs[n][k], k contiguous (B transposed)

    const int tid = threadIdx.x;
    const int m0 = blockIdx.y * 128;
    const int n0 = blockIdx.x * 128;

    // staging maps
    const int saM = tid >> 1;              // 0..127
    const int saK = (tid & 1) * 16;        // 0 or 16
    const int sbK = tid >> 3;              // 0..31
    const int sbN = (tid & 7) * 16;        // 0..112

    // compute maps
    const int wid = tid >> 6;
    const int wx = wid & 1, wy = wid >> 1; // 2x2 wave grid
    const int lane = tid & 63;
    const int c16 = lane & 15;
    const int quad = lane >> 4;

    const TA* Aptr = A + (size_t)(m0 + saM) * lda + saK;
    const float* Bptr = Bm + (size_t)sbK * N + n0 + sbN;

    f32x4 acc[4][4];
    #pragma unroll
    for (int i = 0; i < 4; ++i)
        #pragma unroll
        for (int j = 0; j < 4; ++j) acc[i][j] = (f32x4){0.f, 0.f, 0.f, 0.f};

    // preload K-tile 0
    float ra[4][4];     // A: 4 groups of 4 consecutive k
    float rb[4][4];     // B: 4 groups of 4 consecutive n
    #pragma unroll
    for (int i = 0; i < 4; ++i) load_a4<TA>(Aptr + i * 4, ra[i]);
    #pragma unroll
    for (int i = 0; i < 4; ++i) {
        float4 v = load4(Bptr + i * 4);
        rb[i][0] = v.x; rb[i][1] = v.y; rb[i][2] = v.z; rb[i][3] = v.w;
    }

    for (int k0 = 0; k0 < K; k0 += 32) {
        __syncthreads();   // previous iteration's frag reads complete
        // stage A (k-contiguous: packed b64 writes)
        #pragma unroll
        for (int i = 0; i < 4; ++i) {
            short4v pk = { (short)f2bf(ra[i][0]), (short)f2bf(ra[i][1]),
                           (short)f2bf(ra[i][2]), (short)f2bf(ra[i][3]) };
            *(short4v*)&As[saM][saK + i * 4] = pk;
        }
        // stage B transposed (scalar b16 scatter)
        #pragma unroll
        for (int i = 0; i < 4; ++i)
            #pragma unroll
            for (int j = 0; j < 4; ++j)
                Bs[sbN + i * 4 + j][sbK] = (short)f2bf(rb[i][j]);
        __syncthreads();

        // prefetch next K-tile while MFMAs run
        if (k0 + 32 < K) {
            #pragma unroll
            for (int i = 0; i < 4; ++i) load_a4<TA>(Aptr + k0 + 32 + i * 4, ra[i]);
            #pragma unroll
            for (int i = 0; i < 4; ++i) {
                float4 v = load4(Bptr + (size_t)(k0 + 32) * N + i * 4);
                rb[i][0] = v.x; rb[i][1] = v.y; rb[i][2] = v.z; rb[i][3] = v.w;
            }
        }

        bf16x8 af[4], bf[4];
        #pragma unroll
        for (int mt = 0; mt < 4; ++mt)
            af[mt] = *(const bf16x8*)&As[wy * 64 + mt * 16 + c16][quad * 8];
        #pragma unroll
        for (int nt = 0; nt < 4; ++nt)
            bf[nt] = *(const bf16x8*)&Bs[wx * 64 + nt * 16 + c16][quad * 8];

        #pragma unroll
        for (int mt = 0; mt < 4; ++mt)
            #pragma unroll
            for (int nt = 0; nt < 4; ++nt)
                acc[mt][nt] = __builtin_amdgcn_mfma_f32_16x16x32_bf16(
                    af[mt], bf[nt], acc[mt][nt], 0, 0, 0);
    }

    // epilogue: D row = quad*4 + r, col = c16 (within each 16x16 tile)
    #pragma unroll
    for (int mt = 0; mt < 4; ++mt) {
        #pragma unroll
        for (int r = 0; r < 4; ++r) {
            int row = m0 + wy * 64 + mt * 16 + quad * 4 + r;
            TC* cp = C + (size_t)row * N + n0 + wx * 64;
            #pragma unroll
            for (int nt = 0; nt < 4; ++nt)
                cp[nt * 16 + c16] = (TC)acc[mt][nt][r];
        }
    }
}

// ---------------------------------------------------------------------------
// Recurrence, 4 waves per (b,h) chain; lgkm-only barriers so the depth-2
// global prefetch and the per-step h store stay in flight across steps.
// ---------------------------------------------------------------------------
__device__ __forceinline__ float lane_bcast(float v, int lane) {
    return __int_as_float(__builtin_amdgcn_readlane(__float_as_int(v), lane));
}

__global__ __launch_bounds__(256, 1) void recur_kernel(bf16* __restrict__ proj,
                                                       const float* __restrict__ sw) {
    const int tid = threadIdx.x;
    const int e = tid & 63;
    const int bh = blockIdx.x;              // 0..127
    const int b = bh >> 4;
    const int h = bh & 15;
    const int d0 = __builtin_amdgcn_readfirstlane((tid >> 6) << 4);
    const int w = d0 >> 4;

    __shared__ float2 part_rf[4][64];
    __shared__ float  part_c[4][64];

    const float* Wc_p = sw + (size_t)h * 4096 + (size_t)d0 * 64 + e;
    const float* Wf_p = Wc_p + (size_t)16 * 4096;
    const float* Wr_p = Wc_p + (size_t)32 * 4096;

    float Wc[16], Wf[16], Wr[16];
    #pragma unroll
    for (int d = 0; d < 16; ++d) {
        Wc[d] = Wc_p[d * 64];
        Wf[d] = Wf_p[d * 64];
        Wr[d] = Wr_p[d * 64];
    }

    bf16* xi_p = proj + (size_t)b * S_ * PROJ4 + h * 64 + e;   // cols [0:1024)
    const bf16* xf_p = xi_p + 1024;
    const bf16* xr_p = xi_p + 2048;

    float hreg = 0.0f;

    float xi0 = __bfloat162float(xi_p[0]);
    float xf0 = __bfloat162float(xf_p[0]);
    float xr0 = __bfloat162float(xr_p[0]);
    float xi1 = __bfloat162float(xi_p[PROJ4]);
    float xf1 = __bfloat162float(xf_p[PROJ4]);
    float xr1 = __bfloat162float(xr_p[PROJ4]);

    for (int t = 0; t < S_; ++t) {
        float xi2 = 0.f, xf2 = 0.f, xr2 = 0.f;
        if (t + 2 < S_) {
            size_t o = (size_t)(t + 2) * PROJ4;
            xi2 = __bfloat162float(xi_p[o]);
            xf2 = __bfloat162float(xf_p[o]);
            xr2 = __bfloat162float(xr_p[o]);
        }

        float ar0 = 0.f, ar1 = 0.f, af0 = 0.f, af1 = 0.f;
        #pragma unroll
        for (int d = 0; d < 16; d += 2) {
            float hv0 = lane_bcast(hreg, d0 + d);
            float hv1 = lane_bcast(hreg, d0 + d + 1);
            ar0 = fmaf(hv0, Wr[d],     ar0);
            ar1 = fmaf(hv1, Wr[d + 1], ar1);
            af0 = fmaf(hv0, Wf[d],     af0);
            af1 = fmaf(hv1, Wf[d + 1], af1);
        }
        part_rf[w][e] = make_float2(ar0 + ar1, af0 + af1);
        BARRIER_LGKM();                                    // barrier 1

        float sr = xr0, sf = xf0;
        #pragma unroll
        for (int ww = 0; ww < 4; ++ww) {
            float2 p = part_rf[ww][e];
            sr += p.x;
            sf += p.y;
        }
        float r = 1.f / (1.f + __expf(-sr));
        float f = 1.f / (1.f + __expf(-sf));

        float rh = r * hreg;
        float ac0 = 0.f, ac1 = 0.f;
        #pragma unroll
        for (int d = 0; d < 16; d += 2) {
            ac0 = fmaf(lane_bcast(rh, d0 + d),     Wc[d],     ac0);
            ac1 = fmaf(lane_bcast(rh, d0 + d + 1), Wc[d + 1], ac1);
        }
        part_c[w][e] = ac0 + ac1;
        BARRIER_LGKM();                                    // barrier 2

        float sc = xi0 + part_c[0][e] + part_c[1][e] + part_c[2][e] + part_c[3][e];
        sc = fminf(fmaxf(sc, -15.f), 15.f);
        float ex = __expf(-2.f * sc);
        float c = (1.f - ex) / (1.f + ex);                 // tanh

        hreg = f * hreg + (1.f - f) * c;                   // identical in all waves
        if (w == 0)
            xi_p[(size_t)t * PROJ4] = __float2bfloat16(hreg);

        xi0 = xi1; xf0 = xf1; xr0 = xr1;
        xi1 = xi2; xf1 = xf2; xr1 = xr2;
    }
}

// ---------------------------------------------------------------------------
// Gated RMSNorm in place over proj cols [0:1024).
// ---------------------------------------------------------------------------
__global__ __launch_bounds__(256) void gate_norm_kernel(bf16* __restrict__ proj,
                                                        const float* __restrict__ nw) {
    const int row = blockIdx.x;
    const int tid = threadIdx.x;
    __shared__ float red[4];

    bf16* hp = proj + (size_t)row * PROJ4;
    const bf16* gp = hp + 3 * DSTATE;

    float4 hv = load4(hp + tid * 4);
    float4 gv = load4(gp + tid * 4);

    float v0 = hv.x * (gv.x / (1.f + __expf(-gv.x)));
    float v1 = hv.y * (gv.y / (1.f + __expf(-gv.y)));
    float v2 = hv.z * (gv.z / (1.f + __expf(-gv.z)));
    float v3 = hv.w * (gv.w / (1.f + __expf(-gv.w)));

    float ss = v0 * v0 + v1 * v1 + v2 * v2 + v3 * v3;
    #pragma unroll
    for (int mask = 32; mask >= 1; mask >>= 1)
        ss += __shfl_xor(ss, mask, 64);

    const int wid = tid >> 6;
    if ((tid & 63) == 0) red[wid] = ss;
    __syncthreads();
    float tot = red[0] + red[1] + red[2] + red[3];
    float scale = rsqrtf(tot * (1.0f / (float)DSTATE) + 1e-6f);

    float4 nv = *(const float4*)(nw + tid * 4);
    float4 y;
    y.x = v0 * scale * nv.x;
    y.y = v1 * scale * nv.y;
    y.z = v2 * scale * nv.z;
    y.w = v3 * scale * nv.w;
    store4(hp + tid * 4, y);
}

// ---------------------------------------------------------------------------
extern "C" void kernel_launch(void* const* d_in, const int* in_sizes, int n_in,
                              void* d_out, int out_size, void* d_ws, size_t ws_size,
                              hipStream_t stream) {
    const float* x     = (const float*)d_in[0];   // [B,S,DIN]
    const float* w_in  = (const float*)d_in[1];   // [DIN, 4*DSTATE]
    const float* sw    = (const float*)d_in[2];   // [3H, DH, DH]
    const float* nw    = (const float*)d_in[3];   // [DSTATE]
    const float* w_out = (const float*)d_in[4];   // [DSTATE, DOUT]
    float* out = (float*)d_out;

    bf16* proj = (bf16*)d_ws;    // [B*S, 4096] bf16 = 134 MB (only ws use)

    // 1) input projection GEMM (MFMA bf16): [16384,1024] @ [1024,4096] -> bf16
    dim3 g1(PROJ4 / 128, (B_ * S_) / 128);
    gemm_mfma<float, bf16><<<g1, 256, 0, stream>>>(x, w_in, proj,
                                                   B_ * S_, PROJ4, DIN, DIN);

    // 2) sequential gated recurrence: 4 waves/chain, h_t overwrites xi slot
    recur_kernel<<<128, 256, 0, stream>>>(proj, sw);

    // 3) gate + rmsnorm in place over cols 0:1024
    gate_norm_kernel<<<B_ * S_, 256, 0, stream>>>(proj, nw);

    // 4) output projection GEMM (MFMA bf16): y(bf16, lda=4096) @ [1024,1024] -> f32
    dim3 g2(DSTATE / 128, (B_ * S_) / 128);
    gemm_mfma<bf16, float><<<g2, 256, 0, stream>>>(proj, w_out, out,
                                                   B_ * S_, DSTATE, DSTATE, PROJ4);
}

// Round 5
// 2268.367 us; speedup vs baseline: 1.7616x; 1.0378x over previous
//
#include <hip/hip_runtime.h>
#include <hip/hip_bf16.h>
#include <math.h>

typedef __hip_bfloat16 bf16;

// Problem constants (fixed by reference)
#define B_      8
#define S_      2048
#define DIN     1024
#define DSTATE  1024
#define H_      16
#define DH_     64
#define PROJ4   4096   // 4*DSTATE

// Barrier that does NOT drain vmcnt: LDS ordering only. Keeps global
// prefetch loads / stores in flight across the barrier.
#define BARRIER_LGKM() asm volatile("s_waitcnt lgkmcnt(0)\n\ts_barrier" ::: "memory")

// ---------------------------------------------------------------------------
// bf16 <-> f32 helpers (bit-level, RNE for store)
// ---------------------------------------------------------------------------
__device__ __forceinline__ unsigned short f2bf(float f) {
    unsigned int x = __float_as_uint(f);
    x += 0x7FFFu + ((x >> 16) & 1u);   // round-to-nearest-even
    return (unsigned short)(x >> 16);
}

__device__ __forceinline__ float4 load4(const float* p) { return *(const float4*)p; }
__device__ __forceinline__ float4 load4(const bf16* p) {
    uint2 u = *(const uint2*)p;    // 4 bf16 = 8 bytes
    float4 r;
    r.x = __uint_as_float((u.x & 0xFFFFu) << 16);
    r.y = __uint_as_float(u.x & 0xFFFF0000u);
    r.z = __uint_as_float((u.y & 0xFFFFu) << 16);
    r.w = __uint_as_float(u.y & 0xFFFF0000u);
    return r;
}
__device__ __forceinline__ void store4(float* p, float4 v) { *(float4*)p = v; }
__device__ __forceinline__ void store4(bf16* p, float4 v) {
    uint2 u;
    u.x = (unsigned int)f2bf(v.x) | ((unsigned int)f2bf(v.y) << 16);
    u.y = (unsigned int)f2bf(v.z) | ((unsigned int)f2bf(v.w) << 16);
    *(uint2*)p = u;
}

// ---------------------------------------------------------------------------
// MFMA bf16 GEMM: C[M,N] = A[M,K] @ B[K,N]; A row stride lda; B,C dense.
// 128x128 tile, BK=32, 256 threads = 4 waves (2x2), each wave 64x64 via a
// 4x4 grid of mfma_f32_16x16x32_bf16. fp32 operands converted to bf16 during
// LDS staging. (Unchanged from R4 — recur is this round's target.)
// ---------------------------------------------------------------------------
typedef __attribute__((ext_vector_type(8))) short bf16x8;
typedef __attribute__((ext_vector_type(4))) float f32x4;
typedef __attribute__((ext_vector_type(4))) short short4v;

template <typename TA>
__device__ __forceinline__ void load_a4(const TA* p, float out[4]);
template <>
__device__ __forceinline__ void load_a4<float>(const float* p, float out[4]) {
    float4 v = *(const float4*)p;
    out[0] = v.x; out[1] = v.y; out[2] = v.z; out[3] = v.w;
}
template <>
__device__ __forceinline__ void load_a4<bf16>(const bf16* p, float out[4]) {
    float4 v = load4(p);
    out[0] = v.x; out[1] = v.y; out[2] = v.z; out[3] = v.w;
}

template <typename TA, typename TC>
__global__ __launch_bounds__(256) void gemm_mfma(const TA* __restrict__ A,
                                                 const float* __restrict__ Bm,
                                                 TC* __restrict__ C,
                                                 int M, int N, int K, int lda) {
    __shared__ short As[128][40];   // As[m][k], k contiguous
    __shared__ short Bs[128][40];   // Bs[n][k], k contiguous (B transposed)

    const int tid = threadIdx.x;
    const int m0 = blockIdx.y * 128;
    const int n0 = blockIdx.x * 128;

    const int saM = tid >> 1;              // 0..127
    const int saK = (tid & 1) * 16;        // 0 or 16
    const int sbK = tid >> 3;              // 0..31
    const int sbN = (tid & 7) * 16;        // 0..112

    const int wid = tid >> 6;
    const int wx = wid & 1, wy = wid >> 1; // 2x2 wave grid
    const int lane = tid & 63;
    const int c16 = lane & 15;
    const int quad = lane >> 4;

    const TA* Aptr = A + (size_t)(m0 + saM) * lda + saK;
    const float* Bptr = Bm + (size_t)sbK * N + n0 + sbN;

    f32x4 acc[4][4];
    #pragma unroll
    for (int i = 0; i < 4; ++i)
        #pragma unroll
        for (int j = 0; j < 4; ++j) acc[i][j] = (f32x4){0.f, 0.f, 0.f, 0.f};

    float ra[4][4];
    float rb[4][4];
    #pragma unroll
    for (int i = 0; i < 4; ++i) load_a4<TA>(Aptr + i * 4, ra[i]);
    #pragma unroll
    for (int i = 0; i < 4; ++i) {
        float4 v = load4(Bptr + i * 4);
        rb[i][0] = v.x; rb[i][1] = v.y; rb[i][2] = v.z; rb[i][3] = v.w;
    }

    for (int k0 = 0; k0 < K; k0 += 32) {
        __syncthreads();
        #pragma unroll
        for (int i = 0; i < 4; ++i) {
            short4v pk = { (short)f2bf(ra[i][0]), (short)f2bf(ra[i][1]),
                           (short)f2bf(ra[i][2]), (short)f2bf(ra[i][3]) };
            *(short4v*)&As[saM][saK + i * 4] = pk;
        }
        #pragma unroll
        for (int i = 0; i < 4; ++i)
            #pragma unroll
            for (int j = 0; j < 4; ++j)
                Bs[sbN + i * 4 + j][sbK] = (short)f2bf(rb[i][j]);
        __syncthreads();

        if (k0 + 32 < K) {
            #pragma unroll
            for (int i = 0; i < 4; ++i) load_a4<TA>(Aptr + k0 + 32 + i * 4, ra[i]);
            #pragma unroll
            for (int i = 0; i < 4; ++i) {
                float4 v = load4(Bptr + (size_t)(k0 + 32) * N + i * 4);
                rb[i][0] = v.x; rb[i][1] = v.y; rb[i][2] = v.z; rb[i][3] = v.w;
            }
        }

        bf16x8 af[4], bf[4];
        #pragma unroll
        for (int mt = 0; mt < 4; ++mt)
            af[mt] = *(const bf16x8*)&As[wy * 64 + mt * 16 + c16][quad * 8];
        #pragma unroll
        for (int nt = 0; nt < 4; ++nt)
            bf[nt] = *(const bf16x8*)&Bs[wx * 64 + nt * 16 + c16][quad * 8];

        #pragma unroll
        for (int mt = 0; mt < 4; ++mt)
            #pragma unroll
            for (int nt = 0; nt < 4; ++nt)
                acc[mt][nt] = __builtin_amdgcn_mfma_f32_16x16x32_bf16(
                    af[mt], bf[nt], acc[mt][nt], 0, 0, 0);
    }

    #pragma unroll
    for (int mt = 0; mt < 4; ++mt) {
        #pragma unroll
        for (int r = 0; r < 4; ++r) {
            int row = m0 + wy * 64 + mt * 16 + quad * 4 + r;
            TC* cp = C + (size_t)row * N + n0 + wx * 64;
            #pragma unroll
            for (int nt = 0; nt < 4; ++nt)
                cp[nt * 16 + c16] = (TC)acc[mt][nt][r];
        }
    }
}

// ---------------------------------------------------------------------------
// Recurrence, 4 waves per (b,h) chain, NO global memory on the critical path:
//  - x-inputs flow through an 8-deep LDS ring; wave w (at steps t%4==w)
//    ds_writes data for step t+1 from regs loaded 4 steps (=~8 barriers)
//    earlier, then issues global loads for step t+5. vmcnt waits are always
//    long-satisfied.
//  - h-store to global distributed: wave t%4 stores step t's h (never waited).
//  - lgkm-only barriers (2/step, structurally minimal).
// ---------------------------------------------------------------------------
__device__ __forceinline__ float lane_bcast(float v, int lane) {
    return __int_as_float(__builtin_amdgcn_readlane(__float_as_int(v), lane));
}

__global__ __launch_bounds__(256, 1) void recur_kernel(bf16* __restrict__ proj,
                                                       const float* __restrict__ sw) {
    const int tid = threadIdx.x;
    const int e = tid & 63;
    const int bh = blockIdx.x;              // 0..127
    const int b = bh >> 4;
    const int h = bh & 15;
    const int d0 = __builtin_amdgcn_readfirstlane((tid >> 6) << 4);
    const int w = d0 >> 4;

    __shared__ float2 part_rf[4][64];
    __shared__ float  part_c[4][64];
    __shared__ float  ring[8][3][64];       // [slot][xi/xf/xr][e], 6 KB

    const float* Wc_p = sw + (size_t)h * 4096 + (size_t)d0 * 64 + e;
    const float* Wf_p = Wc_p + (size_t)16 * 4096;
    const float* Wr_p = Wc_p + (size_t)32 * 4096;

    float Wc[16], Wf[16], Wr[16];
    #pragma unroll
    for (int d = 0; d < 16; ++d) {
        Wc[d] = Wc_p[d * 64];
        Wf[d] = Wf_p[d * 64];
        Wr[d] = Wr_p[d * 64];
    }

    bf16* xi_p = proj + (size_t)b * S_ * PROJ4 + h * 64 + e;   // cols [0:1024)
    const bf16* xf_p = xi_p + 1024;
    const bf16* xr_p = xi_p + 2048;

    // Prologue: wave w pre-loads step w+1 into regs; wave 0 seeds ring slot 0.
    float rxi, rxf, rxr;
    {
        size_t o = (size_t)(w + 1) * PROJ4;
        rxi = __bfloat162float(xi_p[o]);
        rxf = __bfloat162float(xf_p[o]);
        rxr = __bfloat162float(xr_p[o]);
        if (w == 0) {
            ring[0][0][e] = __bfloat162float(xi_p[0]);
            ring[0][1][e] = __bfloat162float(xf_p[0]);
            ring[0][2][e] = __bfloat162float(xr_p[0]);
        }
    }
    __syncthreads();

    float hreg = 0.0f;

    for (int t = 0; t < S_; ++t) {
        // Turn work: publish step t+1's inputs to the ring (loaded 4 steps
        // ago); refill regs with step t+5. Wave-uniform branch.
        if ((t & 3) == w) {
            int s = (t + 1) & 7;
            ring[s][0][e] = rxi;
            ring[s][1][e] = rxf;
            ring[s][2][e] = rxr;
            if (t + 5 < S_) {
                size_t o = (size_t)(t + 5) * PROJ4;
                rxi = __bfloat162float(xi_p[o]);
                rxf = __bfloat162float(xf_p[o]);
                rxr = __bfloat162float(xr_p[o]);
            }
        }

        // r/f partial matvecs over this wave's d-slice
        float ar0 = 0.f, ar1 = 0.f, af0 = 0.f, af1 = 0.f;
        #pragma unroll
        for (int d = 0; d < 16; d += 2) {
            float hv0 = lane_bcast(hreg, d0 + d);
            float hv1 = lane_bcast(hreg, d0 + d + 1);
            ar0 = fmaf(hv0, Wr[d],     ar0);
            ar1 = fmaf(hv1, Wr[d + 1], ar1);
            af0 = fmaf(hv0, Wf[d],     af0);
            af1 = fmaf(hv1, Wf[d + 1], af1);
        }
        part_rf[w][e] = make_float2(ar0 + ar1, af0 + af1);
        BARRIER_LGKM();                                    // barrier 1

        const int cs = t & 7;
        float xr0 = ring[cs][2][e];
        float xf0 = ring[cs][1][e];
        float xi0 = ring[cs][0][e];

        float sr = xr0, sf = xf0;
        #pragma unroll
        for (int ww = 0; ww < 4; ++ww) {
            float2 p = part_rf[ww][e];
            sr += p.x;
            sf += p.y;
        }
        float r = 1.f / (1.f + __expf(-sr));
        float f = 1.f / (1.f + __expf(-sf));

        float rh = r * hreg;
        float ac0 = 0.f, ac1 = 0.f;
        #pragma unroll
        for (int d = 0; d < 16; d += 2) {
            ac0 = fmaf(lane_bcast(rh, d0 + d),     Wc[d],     ac0);
            ac1 = fmaf(lane_bcast(rh, d0 + d + 1), Wc[d + 1], ac1);
        }
        part_c[w][e] = ac0 + ac1;
        BARRIER_LGKM();                                    // barrier 2

        float sc = xi0 + part_c[0][e] + part_c[1][e] + part_c[2][e] + part_c[3][e];
        sc = fminf(fmaxf(sc, -15.f), 15.f);
        float ex = __expf(-2.f * sc);
        float c = (1.f - ex) / (1.f + ex);                 // tanh

        hreg = f * hreg + (1.f - f) * c;                   // identical in all waves

        // distributed h-store (fire-and-forget; never waited on)
        if ((t & 3) == w)
            xi_p[(size_t)t * PROJ4] = __float2bfloat16(hreg);
    }
}

// ---------------------------------------------------------------------------
// Gated RMSNorm in place over proj cols [0:1024).
// ---------------------------------------------------------------------------
__global__ __launch_bounds__(256) void gate_norm_kernel(bf16* __restrict__ proj,
                                                        const float* __restrict__ nw) {
    const int row = blockIdx.x;
    const int tid = threadIdx.x;
    __shared__ float red[4];

    bf16* hp = proj + (size_t)row * PROJ4;
    const bf16* gp = hp + 3 * DSTATE;

    float4 hv = load4(hp + tid * 4);
    float4 gv = load4(gp + tid * 4);

    float v0 = hv.x * (gv.x / (1.f + __expf(-gv.x)));
    float v1 = hv.y * (gv.y / (1.f + __expf(-gv.y)));
    float v2 = hv.z * (gv.z / (1.f + __expf(-gv.z)));
    float v3 = hv.w * (gv.w / (1.f + __expf(-gv.w)));

    float ss = v0 * v0 + v1 * v1 + v2 * v2 + v3 * v3;
    #pragma unroll
    for (int mask = 32; mask >= 1; mask >>= 1)
        ss += __shfl_xor(ss, mask, 64);

    const int wid = tid >> 6;
    if ((tid & 63) == 0) red[wid] = ss;
    __syncthreads();
    float tot = red[0] + red[1] + red[2] + red[3];
    float scale = rsqrtf(tot * (1.0f / (float)DSTATE) + 1e-6f);

    float4 nv = *(const float4*)(nw + tid * 4);
    float4 y;
    y.x = v0 * scale * nv.x;
    y.y = v1 * scale * nv.y;
    y.z = v2 * scale * nv.z;
    y.w = v3 * scale * nv.w;
    store4(hp + tid * 4, y);
}

// ---------------------------------------------------------------------------
extern "C" void kernel_launch(void* const* d_in, const int* in_sizes, int n_in,
                              void* d_out, int out_size, void* d_ws, size_t ws_size,
                              hipStream_t stream) {
    const float* x     = (const float*)d_in[0];   // [B,S,DIN]
    const float* w_in  = (const float*)d_in[1];   // [DIN, 4*DSTATE]
    const float* sw    = (const float*)d_in[2];   // [3H, DH, DH]
    const float* nw    = (const float*)d_in[3];   // [DSTATE]
    const float* w_out = (const float*)d_in[4];   // [DSTATE, DOUT]
    float* out = (float*)d_out;

    bf16* proj = (bf16*)d_ws;    // [B*S, 4096] bf16 = 134 MB (only ws use)

    // 1) input projection GEMM (MFMA bf16): [16384,1024] @ [1024,4096] -> bf16
    dim3 g1(PROJ4 / 128, (B_ * S_) / 128);
    gemm_mfma<float, bf16><<<g1, 256, 0, stream>>>(x, w_in, proj,
                                                   B_ * S_, PROJ4, DIN, DIN);

    // 2) sequential gated recurrence: 4 waves/chain, LDS ring for inputs
    recur_kernel<<<128, 256, 0, stream>>>(proj, sw);

    // 3) gate + rmsnorm in place over cols 0:1024
    gate_norm_kernel<<<B_ * S_, 256, 0, stream>>>(proj, nw);

    // 4) output projection GEMM (MFMA bf16): y(bf16, lda=4096) @ [1024,1024] -> f32
    dim3 g2(DSTATE / 128, (B_ * S_) / 128);
    gemm_mfma<bf16, float><<<g2, 256, 0, stream>>>(proj, w_out, out,
                                                   B_ * S_, DSTATE, DSTATE, PROJ4);
}